// Round 1
// baseline (11863.479 us; speedup 1.0000x reference)
//
#include <hip/hip_runtime.h>
#include <hip/hip_bf16.h>
#include <stdint.h>

typedef unsigned short ushort_t;
using bf16x8 = __attribute__((ext_vector_type(8))) short;
using f32x4  = __attribute__((ext_vector_type(4))) float;

#define SEQ    256
#define BATCH  64
#define INDIM  512
#define HDIM   1024
#define OUTDIM 256
#define MTOT   (SEQ*BATCH)   // 16384
#define GBLK   64            // scan grid blocks

__device__ __forceinline__ ushort_t f2bf(float f) {
  uint32_t u = __builtin_bit_cast(uint32_t, f);
  u += 0x7fffu + ((u >> 16) & 1u);
  return (ushort_t)(u >> 16);
}
__device__ __forceinline__ float bf2f(ushort_t b) {
  uint32_t u = ((uint32_t)b) << 16;
  return __builtin_bit_cast(float, u);
}
__device__ __forceinline__ f32x4 mfma16(bf16x8 a, bf16x8 b, f32x4 c) {
  return __builtin_amdgcn_mfma_f32_16x16x32_bf16(a, b, c, 0, 0, 0);
}
__device__ __forceinline__ void gload16(const void* g, void* l) {
  __builtin_amdgcn_global_load_lds(
      (const __attribute__((address_space(1))) unsigned int*)g,
      (__attribute__((address_space(3))) unsigned int*)l, 16, 0, 0);
}

// ---------------- prep kernels ----------------
__global__ void k_convert(const float* __restrict__ src, ushort_t* __restrict__ dst, int n) {
  int i = blockIdx.x * blockDim.x + threadIdx.x;
  if (i < n) dst[i] = f2bf(src[i]);
}
__global__ void k_split(const float* __restrict__ src, ushort_t* __restrict__ hi,
                        ushort_t* __restrict__ lo, int n) {
  int i = blockIdx.x * blockDim.x + threadIdx.x;
  if (i < n) {
    float v = src[i];
    ushort_t h = f2bf(v);
    hi[i] = h;
    lo[i] = f2bf(v - bf2f(h));
  }
}
// de-interleave W_c [H, 2H] into Wi (input half) and Wh (hidden half), hi/lo split
__global__ void k_split_wc(const float* __restrict__ Wc,
                           ushort_t* __restrict__ WiH, ushort_t* __restrict__ WiL,
                           ushort_t* __restrict__ WhH, ushort_t* __restrict__ WhL) {
  int i = blockIdx.x * blockDim.x + threadIdx.x;
  if (i < HDIM * HDIM) {
    int row = i >> 10, k = i & 1023;
    float vi = Wc[(size_t)row * (2 * HDIM) + k];
    float vh = Wc[(size_t)row * (2 * HDIM) + HDIM + k];
    ushort_t ih = f2bf(vi);
    WiH[i] = ih; WiL[i] = f2bf(vi - bf2f(ih));
    ushort_t hh = f2bf(vh);
    WhH[i] = hh; WhL[i] = f2bf(vh - bf2f(hh));
  }
}

// ---------------- generic NT GEMM: C[M,N] = act(A[M,K] * B[N,K]^T + bias) ------------
// m97-style: 128x128 tile, BK=32, global_load_lds staging, 4 waves 2x2, 4x4 16x16 tiles each.
template<int SPLITB, int RELU, int OUTBF>
__global__ __launch_bounds__(256) void gemm_nt(
    const ushort_t* __restrict__ A, const ushort_t* __restrict__ Bhi,
    const ushort_t* __restrict__ Blo, const float* __restrict__ bias,
    float* __restrict__ Cf, ushort_t* __restrict__ Cb,
    int M, int N, int K)
{
  __shared__ ushort_t As[128 * 32];
  __shared__ ushort_t Bh[128 * 32];
  __shared__ ushort_t Bl[128 * 32];
  const int tid = threadIdx.x;
  const int w = tid >> 6, l = tid & 63;
  const int m0 = blockIdx.x * 128, n0 = blockIdx.y * 128;
  const int wr = w >> 1, wc = w & 1;
  const int lr = l & 15, lk = l >> 4;

  f32x4 acc[4][4] = {};
  const int nK = K >> 5;
  const size_t rowB = (size_t)K * 2;  // bytes per row

  for (int kk = 0; kk < nK; ++kk) {
    const size_t kbyte = (size_t)kk * 64;
#pragma unroll
    for (int j = 0; j < 2; ++j) {
      int c = (w * 2 + j) * 64 + l;      // 0..511 chunk id (16B chunks)
      int row = c >> 2;
      int kb = (c & 3) * 16;
      gload16((const char*)A + (size_t)(m0 + row) * rowB + kbyte + kb,
              (char*)As + (w * 2 + j) * 1024);
      gload16((const char*)Bhi + (size_t)(n0 + row) * rowB + kbyte + kb,
              (char*)Bh + (w * 2 + j) * 1024);
      if (SPLITB)
        gload16((const char*)Blo + (size_t)(n0 + row) * rowB + kbyte + kb,
                (char*)Bl + (w * 2 + j) * 1024);
    }
    __syncthreads();
    bf16x8 af[4], bhf[4], blf[4];
#pragma unroll
    for (int i = 0; i < 4; ++i) {
      af[i]  = *(const bf16x8*)&As[(wr * 64 + i * 16 + lr) * 32 + lk * 8];
      bhf[i] = *(const bf16x8*)&Bh[(wc * 64 + i * 16 + lr) * 32 + lk * 8];
      if (SPLITB)
        blf[i] = *(const bf16x8*)&Bl[(wc * 64 + i * 16 + lr) * 32 + lk * 8];
    }
#pragma unroll
    for (int i = 0; i < 4; ++i)
#pragma unroll
      for (int j2 = 0; j2 < 4; ++j2) {
        acc[i][j2] = mfma16(af[i], bhf[j2], acc[i][j2]);
        if (SPLITB) acc[i][j2] = mfma16(af[i], blf[j2], acc[i][j2]);
      }
    __syncthreads();
  }
  // epilogue: D layout col = lane&15, row = (lane>>4)*4 + reg
#pragma unroll
  for (int j2 = 0; j2 < 4; ++j2) {
    int n = n0 + wc * 64 + j2 * 16 + lr;
    float bv = bias ? bias[n] : 0.0f;
#pragma unroll
    for (int i = 0; i < 4; ++i) {
#pragma unroll
      for (int r = 0; r < 4; ++r) {
        int m = m0 + wr * 64 + i * 16 + lk * 4 + r;
        float v = acc[i][j2][r] + bv;
        if (RELU) v = fmaxf(v, 0.0f);
        if (OUTBF) Cb[(size_t)m * N + n] = f2bf(v);
        else       Cf[(size_t)m * N + n] = v;
      }
    }
  }
}

// ---------------- grid barrier (agent scope, sense via generation counter) ----------
__device__ __forceinline__ void gridbar(int* bar, int nb) {
  __syncthreads();
  if (threadIdx.x == 0) {
    int g = __hip_atomic_load(&bar[1], __ATOMIC_RELAXED, __HIP_MEMORY_SCOPE_AGENT);
    int prev = __hip_atomic_fetch_add(&bar[0], 1, __ATOMIC_ACQ_REL, __HIP_MEMORY_SCOPE_AGENT);
    if (prev == nb - 1) {
      __hip_atomic_store(&bar[0], 0, __ATOMIC_RELAXED, __HIP_MEMORY_SCOPE_AGENT);
      __hip_atomic_store(&bar[1], g + 1, __ATOMIC_RELEASE, __HIP_MEMORY_SCOPE_AGENT);
    } else {
      while (__hip_atomic_load(&bar[1], __ATOMIC_ACQUIRE, __HIP_MEMORY_SCOPE_AGENT) <= g) {
        __builtin_amdgcn_s_sleep(1);
      }
    }
  }
  __syncthreads();
}

// ---------------- persistent scan kernel ----------------
// 64 blocks x 256 threads. Block owns 16 output cols; wave w owns rows 16w..16w+15.
// Per step: phase A: z0 = P0[t] + h0 @ Wh^T ; h0 += a0*tanh(z0)   (K=1024)
//           phase B: z1 = h0' @ Wi^T + h1 @ Wh^T + b_c ; h1 += a1*tanh(z1)
__global__ __launch_bounds__(256) void scan_kernel(
    const float* __restrict__ P0,
    const ushort_t* __restrict__ WiH, const ushort_t* __restrict__ WiL,
    const ushort_t* __restrict__ WhH, const ushort_t* __restrict__ WhL,
    const float* __restrict__ b_c, const float* __restrict__ taus,
    float* __restrict__ h0f, float* __restrict__ h1f,
    ushort_t* __restrict__ h0b, ushort_t* __restrict__ h1b,   // each 2 x 65536 (double buffered)
    ushort_t* __restrict__ H1buf, float* __restrict__ outHidden, int* __restrict__ bar)
{
  const int blk = blockIdx.x;
  const int tid = threadIdx.x;
  const int w = tid >> 6, l = tid & 63;
  const int lr = l & 15, lk = l >> 4;
  const int c0 = blk * 16;
  const int m0 = w * 16;
  const int n = c0 + lr;       // output col for B-frags / epilogue
  const int mA = m0 + lr;      // A-frag row
  const float a0c = 0.05f / (taus[0] + 0.001f);
  const float a1c = 0.05f / (taus[1] + 0.001f);
  const float bcn = b_c[n];

  for (int t = 0; t < SEQ; ++t) {
    const ushort_t* h0r = h0b + (t & 1) * (BATCH * HDIM);
    ushort_t*       h0w = h0b + ((t + 1) & 1) * (BATCH * HDIM);
    const ushort_t* h1r = h1b + (t & 1) * (BATCH * HDIM);
    ushort_t*       h1w = h1b + ((t + 1) & 1) * (BATCH * HDIM);

    // ---- phase A: layer 0 ----
    const float* P0t = P0 + (size_t)t * (BATCH * HDIM);
    float p0v[4], h0v[4];
#pragma unroll
    for (int r = 0; r < 4; ++r) {
      int m = m0 + lk * 4 + r;
      p0v[r] = P0t[m * HDIM + n];
      h0v[r] = h0f[m * HDIM + n];
    }
    f32x4 aH = {}, aL = {};
#pragma unroll 8
    for (int kk = 0; kk < 32; ++kk) {
      int k = kk * 32 + lk * 8;
      bf16x8 a  = *(const bf16x8*)&h0r[mA * HDIM + k];
      bf16x8 bh = *(const bf16x8*)&WhH[n * HDIM + k];
      bf16x8 bl = *(const bf16x8*)&WhL[n * HDIM + k];
      aH = mfma16(a, bh, aH);
      aL = mfma16(a, bl, aL);
    }
#pragma unroll
    for (int r = 0; r < 4; ++r) {
      int m = m0 + lk * 4 + r;
      float z = aH[r] + aL[r] + p0v[r];
      float h = h0v[r] + a0c * tanhf(z);
      h0f[m * HDIM + n] = h;
      h0w[m * HDIM + n] = f2bf(h);
    }
    gridbar(bar, GBLK);

    // ---- phase B: layer 1 ----
    float h1v[4];
#pragma unroll
    for (int r = 0; r < 4; ++r) h1v[r] = h1f[(m0 + lk * 4 + r) * HDIM + n];
    f32x4 b1 = {}, b2 = {}, b3 = {}, b4 = {};
#pragma unroll 4
    for (int kk = 0; kk < 32; ++kk) {
      int k = kk * 32 + lk * 8;
      bf16x8 ai = *(const bf16x8*)&h0w[mA * HDIM + k];   // h0' (new)
      bf16x8 ah = *(const bf16x8*)&h1r[mA * HDIM + k];   // h1 (old)
      b1 = mfma16(ai, *(const bf16x8*)&WiH[n * HDIM + k], b1);
      b2 = mfma16(ai, *(const bf16x8*)&WiL[n * HDIM + k], b2);
      b3 = mfma16(ah, *(const bf16x8*)&WhH[n * HDIM + k], b3);
      b4 = mfma16(ah, *(const bf16x8*)&WhL[n * HDIM + k], b4);
    }
    ushort_t* H1t = H1buf + (size_t)t * (BATCH * HDIM);
#pragma unroll
    for (int r = 0; r < 4; ++r) {
      int m = m0 + lk * 4 + r;
      float z = b1[r] + b2[r] + b3[r] + b4[r] + bcn;
      float h = h1v[r] + a1c * tanhf(z);
      h1f[m * HDIM + n] = h;
      ushort_t hb = f2bf(h);
      h1w[m * HDIM + n] = hb;
      H1t[m * HDIM + n] = hb;
    }
    gridbar(bar, GBLK);
  }

  // hidden_final: [L=2, B=64, H=1024] fp32
  for (int i = blk * 256 + tid; i < BATCH * HDIM; i += GBLK * 256) {
    outHidden[i] = h0f[i];
    outHidden[BATCH * HDIM + i] = h1f[i];
  }
}

// ---------------- host ----------------
extern "C" void kernel_launch(void* const* d_in, const int* in_sizes, int n_in,
                              void* d_out, int out_size, void* d_ws, size_t ws_size,
                              hipStream_t stream) {
  const float* x    = (const float*)d_in[0];
  const float* W_in = (const float*)d_in[1];
  const float* b_in = (const float*)d_in[2];
  const float* W_c  = (const float*)d_in[3];
  const float* b_c  = (const float*)d_in[4];
  const float* taus = (const float*)d_in[5];
  const float* W_o1 = (const float*)d_in[6];
  const float* b_o1 = (const float*)d_in[7];
  const float* W_o2 = (const float*)d_in[8];
  const float* b_o2 = (const float*)d_in[9];
  float* out = (float*)d_out;

  char* ws = (char*)d_ws;
  size_t off = 0;
  auto alloc = [&](size_t bytes) -> char* {
    char* p = ws + off;
    off += (bytes + 255) & ~(size_t)255;
    return p;
  };
  ushort_t* x_bf  = (ushort_t*)alloc((size_t)MTOT * INDIM * 2);       // 16 MB
  ushort_t* xp_b  = (ushort_t*)alloc((size_t)MTOT * HDIM * 2);        // 32 MB
  float*    P0    = (float*)   alloc((size_t)MTOT * HDIM * 4);        // 64 MB
  ushort_t* H1buf = (ushort_t*)alloc((size_t)MTOT * HDIM * 2);        // 32 MB
  ushort_t* O1    = (ushort_t*)alloc((size_t)MTOT * (HDIM/2) * 2);    // 16 MB
  ushort_t* WiH   = (ushort_t*)alloc((size_t)HDIM * HDIM * 2);
  ushort_t* WiL   = (ushort_t*)alloc((size_t)HDIM * HDIM * 2);
  ushort_t* WhH   = (ushort_t*)alloc((size_t)HDIM * HDIM * 2);
  ushort_t* WhL   = (ushort_t*)alloc((size_t)HDIM * HDIM * 2);
  ushort_t* WinH  = (ushort_t*)alloc((size_t)HDIM * INDIM * 2);
  ushort_t* WinL  = (ushort_t*)alloc((size_t)HDIM * INDIM * 2);
  ushort_t* Wo1b  = (ushort_t*)alloc((size_t)(HDIM/2) * HDIM * 2);
  ushort_t* Wo2b  = (ushort_t*)alloc((size_t)OUTDIM * (HDIM/2) * 2);
  // contiguous state region (memset once per launch)
  char* state = alloc(2 * BATCH * HDIM * 4 + 4 * BATCH * HDIM * 2 + 256);
  float*    h0f = (float*)state;
  float*    h1f = h0f + BATCH * HDIM;
  ushort_t* h0b = (ushort_t*)(h1f + BATCH * HDIM);
  ushort_t* h1b = h0b + 2 * BATCH * HDIM;
  int*      bar = (int*)(h1b + 2 * BATCH * HDIM);
  if (off > ws_size) return;  // workspace too small; fail visibly

  hipMemsetAsync(state, 0, 2 * BATCH * HDIM * 4 + 4 * BATCH * HDIM * 2 + 256, stream);

  // prep
  k_convert<<<(MTOT * INDIM + 255) / 256, 256, 0, stream>>>(x, x_bf, MTOT * INDIM);
  k_split<<<(HDIM * INDIM + 255) / 256, 256, 0, stream>>>(W_in, WinH, WinL, HDIM * INDIM);
  k_split_wc<<<(HDIM * HDIM + 255) / 256, 256, 0, stream>>>(W_c, WiH, WiL, WhH, WhL);
  k_convert<<<((HDIM/2) * HDIM + 255) / 256, 256, 0, stream>>>(W_o1, Wo1b, (HDIM/2) * HDIM);
  k_convert<<<(OUTDIM * (HDIM/2) + 255) / 256, 256, 0, stream>>>(W_o2, Wo2b, OUTDIM * (HDIM/2));

  // xp = x @ W_in^T + b_in   -> bf16
  gemm_nt<1, 0, 1><<<dim3(MTOT / 128, HDIM / 128), 256, 0, stream>>>(
      x_bf, WinH, WinL, b_in, nullptr, xp_b, MTOT, HDIM, INDIM);
  // P0 = xp @ Wi^T + b_c     -> fp32
  gemm_nt<1, 0, 0><<<dim3(MTOT / 128, HDIM / 128), 256, 0, stream>>>(
      xp_b, WiH, WiL, b_c, P0, nullptr, MTOT, HDIM, HDIM);

  // sequential scan
  scan_kernel<<<GBLK, 256, 0, stream>>>(P0, WiH, WiL, WhH, WhL, b_c, taus,
                                        h0f, h1f, h0b, h1b, H1buf,
                                        out + (size_t)SEQ * BATCH * OUTDIM, bar);

  // O1 = relu(H1 @ W_o1^T + b_o1) -> bf16
  gemm_nt<0, 1, 1><<<dim3(MTOT / 128, (HDIM/2) / 128), 256, 0, stream>>>(
      H1buf, Wo1b, nullptr, b_o1, nullptr, O1, MTOT, HDIM / 2, HDIM);
  // out = O1 @ W_o2^T + b_o2 -> fp32 (d_out outputs region)
  gemm_nt<0, 0, 0><<<dim3(MTOT / 128, OUTDIM / 128), 256, 0, stream>>>(
      O1, Wo2b, nullptr, b_o2, out, nullptr, MTOT, OUTDIM, HDIM / 2);
}

// Round 2
// 3671.809 us; speedup vs baseline: 3.2310x; 3.2310x over previous
//
#include <hip/hip_runtime.h>
#include <hip/hip_bf16.h>
#include <stdint.h>

typedef unsigned short ushort_t;
typedef unsigned long long ull_t;
using bf16x8 = __attribute__((ext_vector_type(8))) short;
using f32x4  = __attribute__((ext_vector_type(4))) float;

#define SEQ    256
#define BATCH  64
#define INDIM  512
#define HDIM   1024
#define OUTDIM 256
#define MTOT   (SEQ*BATCH)   // 16384

__device__ __forceinline__ ushort_t f2bf(float f) {
  uint32_t u = __builtin_bit_cast(uint32_t, f);
  u += 0x7fffu + ((u >> 16) & 1u);
  return (ushort_t)(u >> 16);
}
__device__ __forceinline__ float bf2f(ushort_t b) {
  uint32_t u = ((uint32_t)b) << 16;
  return __builtin_bit_cast(float, u);
}
__device__ __forceinline__ f32x4 mfma16(bf16x8 a, bf16x8 b, f32x4 c) {
  return __builtin_amdgcn_mfma_f32_16x16x32_bf16(a, b, c, 0, 0, 0);
}
__device__ __forceinline__ void gload16(const void* g, void* l) {
  __builtin_amdgcn_global_load_lds(
      (const __attribute__((address_space(1))) unsigned int*)g,
      (__attribute__((address_space(3))) unsigned int*)l, 16, 0, 0);
}
__device__ __forceinline__ float tanhfast(float z) {
  float e = __expf(2.0f * z);
  return 1.0f - 2.0f / (e + 1.0f);
}
__device__ __forceinline__ ull_t pack4bf(const float* v) {
  ull_t p = 0;
#pragma unroll
  for (int j = 0; j < 4; ++j) p |= (ull_t)f2bf(v[j]) << (16 * j);
  return p;
}

// ---------------- prep kernels ----------------
__global__ void k_convert(const float* __restrict__ src, ushort_t* __restrict__ dst, int n) {
  int i = blockIdx.x * blockDim.x + threadIdx.x;
  if (i < n) dst[i] = f2bf(src[i]);
}
__global__ void k_split(const float* __restrict__ src, ushort_t* __restrict__ hi,
                        ushort_t* __restrict__ lo, int n) {
  int i = blockIdx.x * blockDim.x + threadIdx.x;
  if (i < n) {
    float v = src[i];
    ushort_t h = f2bf(v);
    hi[i] = h;
    lo[i] = f2bf(v - bf2f(h));
  }
}
__global__ void k_split_wc(const float* __restrict__ Wc,
                           ushort_t* __restrict__ WiH, ushort_t* __restrict__ WiL,
                           ushort_t* __restrict__ WhH, ushort_t* __restrict__ WhL) {
  int i = blockIdx.x * blockDim.x + threadIdx.x;
  if (i < HDIM * HDIM) {
    int row = i >> 10, k = i & 1023;
    float vi = Wc[(size_t)row * (2 * HDIM) + k];
    float vh = Wc[(size_t)row * (2 * HDIM) + HDIM + k];
    ushort_t ih = f2bf(vi);
    WiH[i] = ih; WiL[i] = f2bf(vi - bf2f(ih));
    ushort_t hh = f2bf(vh);
    WhH[i] = hh; WhL[i] = f2bf(vh - bf2f(hh));
  }
}

// ---------------- generic NT GEMM (unchanged from round 1) ----------------
template<int SPLITB, int RELU, int OUTBF>
__global__ __launch_bounds__(256) void gemm_nt(
    const ushort_t* __restrict__ A, const ushort_t* __restrict__ Bhi,
    const ushort_t* __restrict__ Blo, const float* __restrict__ bias,
    float* __restrict__ Cf, ushort_t* __restrict__ Cb,
    int M, int N, int K)
{
  __shared__ ushort_t As[128 * 32];
  __shared__ ushort_t Bh[128 * 32];
  __shared__ ushort_t Bl[128 * 32];
  const int tid = threadIdx.x;
  const int w = tid >> 6, l = tid & 63;
  const int m0 = blockIdx.x * 128, n0 = blockIdx.y * 128;
  const int wr = w >> 1, wc = w & 1;
  const int lr = l & 15, lk = l >> 4;

  f32x4 acc[4][4] = {};
  const int nK = K >> 5;
  const size_t rowB = (size_t)K * 2;

  for (int kk = 0; kk < nK; ++kk) {
    const size_t kbyte = (size_t)kk * 64;
#pragma unroll
    for (int j = 0; j < 2; ++j) {
      int c = (w * 2 + j) * 64 + l;
      int row = c >> 2;
      int kb = (c & 3) * 16;
      gload16((const char*)A + (size_t)(m0 + row) * rowB + kbyte + kb,
              (char*)As + (w * 2 + j) * 1024);
      gload16((const char*)Bhi + (size_t)(n0 + row) * rowB + kbyte + kb,
              (char*)Bh + (w * 2 + j) * 1024);
      if (SPLITB)
        gload16((const char*)Blo + (size_t)(n0 + row) * rowB + kbyte + kb,
                (char*)Bl + (w * 2 + j) * 1024);
    }
    __syncthreads();
    bf16x8 af[4], bhf[4], blf[4];
#pragma unroll
    for (int i = 0; i < 4; ++i) {
      af[i]  = *(const bf16x8*)&As[(wr * 64 + i * 16 + lr) * 32 + lk * 8];
      bhf[i] = *(const bf16x8*)&Bh[(wc * 64 + i * 16 + lr) * 32 + lk * 8];
      if (SPLITB)
        blf[i] = *(const bf16x8*)&Bl[(wc * 64 + i * 16 + lr) * 32 + lk * 8];
    }
#pragma unroll
    for (int i = 0; i < 4; ++i)
#pragma unroll
      for (int j2 = 0; j2 < 4; ++j2) {
        acc[i][j2] = mfma16(af[i], bhf[j2], acc[i][j2]);
        if (SPLITB) acc[i][j2] = mfma16(af[i], blf[j2], acc[i][j2]);
      }
    __syncthreads();
  }
#pragma unroll
  for (int j2 = 0; j2 < 4; ++j2) {
    int n = n0 + wc * 64 + j2 * 16 + lr;
    float bv = bias ? bias[n] : 0.0f;
#pragma unroll
    for (int i = 0; i < 4; ++i) {
#pragma unroll
      for (int r = 0; r < 4; ++r) {
        int m = m0 + wr * 64 + i * 16 + lk * 4 + r;
        float v = acc[i][j2][r] + bv;
        if (RELU) v = fmaxf(v, 0.0f);
        if (OUTBF) Cb[(size_t)m * N + n] = f2bf(v);
        else       Cf[(size_t)m * N + n] = v;
      }
    }
  }
}

// ---------------- persistent scan kernel ----------------
// 256 blocks x 256 threads. Block (g = blk>>6, c = blk&63): rows 16g..16g+15,
// cols 16c..16c+15. 4 independent row-groups, each with its own 64-block flag
// barrier. Per barrier interval (iter i):
//   phase A: h0(i)   = h0(i-1)   + a0*tanh(P0[i] + Wh*h0(i-1))        [i<SEQ]
//   phase B: h1(i-1) = h1(i-2)   + a1*tanh(Wi*h0(i-1) + Wh*h1(i-2) + b_c) [i>=1]
// Weights (16 cols x 256 K slice, hi+lo, Wh+Wi) live in 128 VGPRs per wave.
__global__ __launch_bounds__(256, 1) void scan_kernel(
    const float* __restrict__ P0,
    const ushort_t* __restrict__ WiH, const ushort_t* __restrict__ WiL,
    const ushort_t* __restrict__ WhH, const ushort_t* __restrict__ WhL,
    const float* __restrict__ b_c, const float* __restrict__ taus,
    ushort_t* __restrict__ h0b,     // 2 x 64x1024 bf16 (double buffer)
    ushort_t* __restrict__ H1buf,   // SEQ x 64x1024 bf16 (archive = h1 state)
    float* __restrict__ outHidden, int* __restrict__ flags)
{
  const int blk = blockIdx.x;
  const int g = blk >> 6, c = blk & 63;
  const int tid = threadIdx.x;
  const int w = tid >> 6, l = tid & 63;
  const int lr = l & 15, lk = l >> 4;
  const int colg = c * 16;
  const int rowg = g * 16;
  const int kb = w * 256;

  __shared__ float red[2][4][64][5];   // [phase][wave][lane][reg(+pad)]

  // ---- one-time: weight slices into registers ----
  bf16x8 whh[8], whl[8], wih[8], wil[8];
#pragma unroll
  for (int kk = 0; kk < 8; ++kk) {
    size_t off = (size_t)(colg + lr) * HDIM + kb + kk * 32 + lk * 8;
    whh[kk] = *(const bf16x8*)&WhH[off];
    whl[kk] = *(const bf16x8*)&WhL[off];
    wih[kk] = *(const bf16x8*)&WiH[off];
    wil[kk] = *(const bf16x8*)&WiL[off];
  }

  // wave-0 epilogue mapping: lane l -> row R = l>>2, cols jc..jc+3
  const int R = l >> 2, jc = (l & 3) * 4;
  const int lo_base = 16 * (l >> 4);     // = 16*(R>>2)
  const int ro = (l >> 2) & 3;           // = R&3
  float hm0[4] = {0,0,0,0}, hm1[4] = {0,0,0,0};
  float bc4[4] = {0,0,0,0};
  float a0c = 0.f, a1c = 0.f;
  if (w == 0) {
#pragma unroll
    for (int j = 0; j < 4; ++j) bc4[j] = b_c[colg + jc + j];
    a0c = 0.05f / (taus[0] + 0.001f);
    a1c = 0.05f / (taus[1] + 0.001f);
  }
  int* myflag = &flags[blk * 16];

  for (int i = 0; i <= SEQ; ++i) {
    float4 p0v = make_float4(0.f, 0.f, 0.f, 0.f);
    if (w == 0 && i < SEQ)   // prefetch P0 tile early
      p0v = *(const float4*)&P0[((size_t)i * BATCH + rowg + R) * HDIM + colg + jc];

    f32x4 aA0{}, aA1{}, aI0{}, aI1{}, aH0{}, aH1{};
    const ushort_t* h0r = h0b + ((i + 1) & 1) * (BATCH * HDIM);  // h0(i-1)
    if (i >= 1) {
#pragma unroll
      for (int kk = 0; kk < 8; ++kk) {
        bf16x8 a = *(const bf16x8*)&h0r[(size_t)(rowg + lr) * HDIM + kb + kk * 32 + lk * 8];
        aA0 = mfma16(a, whh[kk], aA0);
        aA1 = mfma16(a, whl[kk], aA1);
        aI0 = mfma16(a, wih[kk], aI0);
        aI1 = mfma16(a, wil[kk], aI1);
      }
    }
    if (i >= 2) {
      const ushort_t* h1r = H1buf + (size_t)(i - 2) * (BATCH * HDIM);
#pragma unroll
      for (int kk = 0; kk < 8; ++kk) {
        bf16x8 a = *(const bf16x8*)&h1r[(size_t)(rowg + lr) * HDIM + kb + kk * 32 + lk * 8];
        aH0 = mfma16(a, whh[kk], aH0);
        aH1 = mfma16(a, whl[kk], aH1);
      }
    }
    f32x4 pA = aA0 + aA1;
    f32x4 pB = (aI0 + aI1) + (aH0 + aH1);
#pragma unroll
    for (int r = 0; r < 4; ++r) {
      red[0][w][l][r] = pA[r];
      red[1][w][l][r] = pB[r];
    }
    __syncthreads();

    if (w == 0) {
      float sA[4], sB[4];
#pragma unroll
      for (int j = 0; j < 4; ++j) {
        float s0 = 0.f, s1 = 0.f;
#pragma unroll
        for (int w4 = 0; w4 < 4; ++w4) {
          s0 += red[0][w4][jc + j + lo_base][ro];
          s1 += red[1][w4][jc + j + lo_base][ro];
        }
        sA[j] = s0; sB[j] = s1;
      }
      if (i < SEQ) {
#pragma unroll
        for (int j = 0; j < 4; ++j)
          hm0[j] += a0c * tanhfast(p0v.x * (j == 0) + p0v.y * (j == 1) +
                                   p0v.z * (j == 2) + p0v.w * (j == 3) + sA[j]);
        ushort_t* h0w = h0b + (i & 1) * (BATCH * HDIM);
        __hip_atomic_store((ull_t*)&h0w[(size_t)(rowg + R) * HDIM + colg + jc],
                           pack4bf(hm0), __ATOMIC_RELAXED, __HIP_MEMORY_SCOPE_AGENT);
      }
      if (i >= 1) {
#pragma unroll
        for (int j = 0; j < 4; ++j)
          hm1[j] += a1c * tanhfast(sB[j] + bc4[j]);
        __hip_atomic_store((ull_t*)&H1buf[(size_t)(i - 1) * (BATCH * HDIM) +
                                          (size_t)(rowg + R) * HDIM + colg + jc],
                           pack4bf(hm1), __ATOMIC_RELAXED, __HIP_MEMORY_SCOPE_AGENT);
      }
      if (i < SEQ)
        __hip_atomic_store(myflag, i + 1, __ATOMIC_RELEASE, __HIP_MEMORY_SCOPE_AGENT);
    }
    if (i < SEQ) {
      if (w == 1) {
        const int target = i + 1;
        int v;
        do {
          v = __hip_atomic_load(&flags[(g * 64 + l) * 16], __ATOMIC_RELAXED,
                                __HIP_MEMORY_SCOPE_AGENT);
        } while (__all(v >= target) == 0);
      }
      __syncthreads();
      __builtin_amdgcn_fence(__ATOMIC_ACQUIRE, "agent");
    }
  }

  if (w == 0) {
    float4 o0 = make_float4(hm0[0], hm0[1], hm0[2], hm0[3]);
    float4 o1 = make_float4(hm1[0], hm1[1], hm1[2], hm1[3]);
    *(float4*)&outHidden[(size_t)(rowg + R) * HDIM + colg + jc] = o0;
    *(float4*)&outHidden[(size_t)(BATCH * HDIM) + (size_t)(rowg + R) * HDIM + colg + jc] = o1;
  }
}

// ---------------- host ----------------
extern "C" void kernel_launch(void* const* d_in, const int* in_sizes, int n_in,
                              void* d_out, int out_size, void* d_ws, size_t ws_size,
                              hipStream_t stream) {
  const float* x    = (const float*)d_in[0];
  const float* W_in = (const float*)d_in[1];
  const float* b_in = (const float*)d_in[2];
  const float* W_c  = (const float*)d_in[3];
  const float* b_c  = (const float*)d_in[4];
  const float* taus = (const float*)d_in[5];
  const float* W_o1 = (const float*)d_in[6];
  const float* b_o1 = (const float*)d_in[7];
  const float* W_o2 = (const float*)d_in[8];
  const float* b_o2 = (const float*)d_in[9];
  float* out = (float*)d_out;

  char* ws = (char*)d_ws;
  size_t off = 0;
  auto alloc = [&](size_t bytes) -> char* {
    char* p = ws + off;
    off += (bytes + 255) & ~(size_t)255;
    return p;
  };
  ushort_t* x_bf  = (ushort_t*)alloc((size_t)MTOT * INDIM * 2);
  ushort_t* xp_b  = (ushort_t*)alloc((size_t)MTOT * HDIM * 2);
  float*    P0    = (float*)   alloc((size_t)MTOT * HDIM * 4);
  ushort_t* H1buf = (ushort_t*)alloc((size_t)MTOT * HDIM * 2);
  ushort_t* O1    = (ushort_t*)alloc((size_t)MTOT * (HDIM/2) * 2);
  ushort_t* WiH   = (ushort_t*)alloc((size_t)HDIM * HDIM * 2);
  ushort_t* WiL   = (ushort_t*)alloc((size_t)HDIM * HDIM * 2);
  ushort_t* WhH   = (ushort_t*)alloc((size_t)HDIM * HDIM * 2);
  ushort_t* WhL   = (ushort_t*)alloc((size_t)HDIM * HDIM * 2);
  ushort_t* WinH  = (ushort_t*)alloc((size_t)HDIM * INDIM * 2);
  ushort_t* WinL  = (ushort_t*)alloc((size_t)HDIM * INDIM * 2);
  ushort_t* Wo1b  = (ushort_t*)alloc((size_t)(HDIM/2) * HDIM * 2);
  ushort_t* Wo2b  = (ushort_t*)alloc((size_t)OUTDIM * (HDIM/2) * 2);
  ushort_t* h0b   = (ushort_t*)alloc((size_t)2 * BATCH * HDIM * 2);
  int*      flags = (int*)     alloc((size_t)256 * 16 * 4);
  if (off > ws_size) return;

  hipMemsetAsync(flags, 0, 256 * 16 * 4, stream);

  k_convert<<<(MTOT * INDIM + 255) / 256, 256, 0, stream>>>(x, x_bf, MTOT * INDIM);
  k_split<<<(HDIM * INDIM + 255) / 256, 256, 0, stream>>>(W_in, WinH, WinL, HDIM * INDIM);
  k_split_wc<<<(HDIM * HDIM + 255) / 256, 256, 0, stream>>>(W_c, WiH, WiL, WhH, WhL);
  k_convert<<<((HDIM/2) * HDIM + 255) / 256, 256, 0, stream>>>(W_o1, Wo1b, (HDIM/2) * HDIM);
  k_convert<<<(OUTDIM * (HDIM/2) + 255) / 256, 256, 0, stream>>>(W_o2, Wo2b, OUTDIM * (HDIM/2));

  // xp = x @ W_in^T + b_in   -> bf16
  gemm_nt<1, 0, 1><<<dim3(MTOT / 128, HDIM / 128), 256, 0, stream>>>(
      x_bf, WinH, WinL, b_in, nullptr, xp_b, MTOT, HDIM, INDIM);
  // P0 = xp @ Wi^T + b_c     -> fp32
  gemm_nt<1, 0, 0><<<dim3(MTOT / 128, HDIM / 128), 256, 0, stream>>>(
      xp_b, WiH, WiL, b_c, P0, nullptr, MTOT, HDIM, HDIM);

  // sequential scan (4 independent row-groups x 64 blocks)
  scan_kernel<<<256, 256, 0, stream>>>(P0, WiH, WiL, WhH, WhL, b_c, taus,
                                       h0b, H1buf,
                                       out + (size_t)SEQ * BATCH * OUTDIM, flags);

  // O1 = relu(H1 @ W_o1^T + b_o1) -> bf16
  gemm_nt<0, 1, 1><<<dim3(MTOT / 128, (HDIM/2) / 128), 256, 0, stream>>>(
      H1buf, Wo1b, nullptr, b_o1, nullptr, O1, MTOT, HDIM / 2, HDIM);
  // out = O1 @ W_o2^T + b_o2 -> fp32
  gemm_nt<0, 0, 0><<<dim3(MTOT / 128, OUTDIM / 128), 256, 0, stream>>>(
      O1, Wo2b, nullptr, b_o2, out, nullptr, MTOT, OUTDIM, HDIM / 2);
}

// Round 3
// 2569.189 us; speedup vs baseline: 4.6176x; 1.4292x over previous
//
#include <hip/hip_runtime.h>
#include <hip/hip_bf16.h>
#include <stdint.h>

typedef unsigned short ushort_t;
typedef unsigned long long ull_t;
using bf16x8 = __attribute__((ext_vector_type(8))) short;
using f32x4  = __attribute__((ext_vector_type(4))) float;

#define SEQ    256
#define BATCH  64
#define INDIM  512
#define HDIM   1024
#define OUTDIM 256
#define MTOT   (SEQ*BATCH)   // 16384

__device__ __forceinline__ ushort_t f2bf(float f) {
  uint32_t u = __builtin_bit_cast(uint32_t, f);
  u += 0x7fffu + ((u >> 16) & 1u);
  return (ushort_t)(u >> 16);
}
__device__ __forceinline__ float bf2f(ushort_t b) {
  uint32_t u = ((uint32_t)b) << 16;
  return __builtin_bit_cast(float, u);
}
__device__ __forceinline__ f32x4 mfma16(bf16x8 a, bf16x8 b, f32x4 c) {
  return __builtin_amdgcn_mfma_f32_16x16x32_bf16(a, b, c, 0, 0, 0);
}
__device__ __forceinline__ void gload16(const void* g, void* l) {
  __builtin_amdgcn_global_load_lds(
      (const __attribute__((address_space(1))) unsigned int*)g,
      (__attribute__((address_space(3))) unsigned int*)l, 16, 0, 0);
}
__device__ __forceinline__ float tanhfast(float z) {
  float e = __expf(2.0f * z);
  return 1.0f - 2.0f / (e + 1.0f);
}
__device__ __forceinline__ ull_t pack4bf(const float* v) {
  ull_t p = 0;
#pragma unroll
  for (int j = 0; j < 4; ++j) p |= (ull_t)f2bf(v[j]) << (16 * j);
  return p;
}
// agent-scope cache-bypassing 16B state load (2 x 8B relaxed atomics -> MALL)
__device__ __forceinline__ bf16x8 aload16(const ushort_t* p) {
  ulonglong2 v;
  v.x = __hip_atomic_load((const ull_t*)p,     __ATOMIC_RELAXED, __HIP_MEMORY_SCOPE_AGENT);
  v.y = __hip_atomic_load((const ull_t*)p + 1, __ATOMIC_RELAXED, __HIP_MEMORY_SCOPE_AGENT);
  return __builtin_bit_cast(bf16x8, v);
}

// ---------------- prep kernels ----------------
__global__ void k_convert(const float* __restrict__ src, ushort_t* __restrict__ dst, int n) {
  int i = blockIdx.x * blockDim.x + threadIdx.x;
  if (i < n) dst[i] = f2bf(src[i]);
}
__global__ void k_split(const float* __restrict__ src, ushort_t* __restrict__ hi,
                        ushort_t* __restrict__ lo, int n) {
  int i = blockIdx.x * blockDim.x + threadIdx.x;
  if (i < n) {
    float v = src[i];
    ushort_t h = f2bf(v);
    hi[i] = h;
    lo[i] = f2bf(v - bf2f(h));
  }
}
__global__ void k_split_wc(const float* __restrict__ Wc,
                           ushort_t* __restrict__ WiH, ushort_t* __restrict__ WiL,
                           ushort_t* __restrict__ WhH, ushort_t* __restrict__ WhL) {
  int i = blockIdx.x * blockDim.x + threadIdx.x;
  if (i < HDIM * HDIM) {
    int row = i >> 10, k = i & 1023;
    float vi = Wc[(size_t)row * (2 * HDIM) + k];
    float vh = Wc[(size_t)row * (2 * HDIM) + HDIM + k];
    ushort_t ih = f2bf(vi);
    WiH[i] = ih; WiL[i] = f2bf(vi - bf2f(ih));
    ushort_t hh = f2bf(vh);
    WhH[i] = hh; WhL[i] = f2bf(vh - bf2f(hh));
  }
}

// ---------------- generic NT GEMM (unchanged) ----------------
template<int SPLITB, int RELU, int OUTBF>
__global__ __launch_bounds__(256) void gemm_nt(
    const ushort_t* __restrict__ A, const ushort_t* __restrict__ Bhi,
    const ushort_t* __restrict__ Blo, const float* __restrict__ bias,
    float* __restrict__ Cf, ushort_t* __restrict__ Cb,
    int M, int N, int K)
{
  __shared__ ushort_t As[128 * 32];
  __shared__ ushort_t Bh[128 * 32];
  __shared__ ushort_t Bl[128 * 32];
  const int tid = threadIdx.x;
  const int w = tid >> 6, l = tid & 63;
  const int m0 = blockIdx.x * 128, n0 = blockIdx.y * 128;
  const int wr = w >> 1, wc = w & 1;
  const int lr = l & 15, lk = l >> 4;

  f32x4 acc[4][4] = {};
  const int nK = K >> 5;
  const size_t rowB = (size_t)K * 2;

  for (int kk = 0; kk < nK; ++kk) {
    const size_t kbyte = (size_t)kk * 64;
#pragma unroll
    for (int j = 0; j < 2; ++j) {
      int c = (w * 2 + j) * 64 + l;
      int row = c >> 2;
      int kb = (c & 3) * 16;
      gload16((const char*)A + (size_t)(m0 + row) * rowB + kbyte + kb,
              (char*)As + (w * 2 + j) * 1024);
      gload16((const char*)Bhi + (size_t)(n0 + row) * rowB + kbyte + kb,
              (char*)Bh + (w * 2 + j) * 1024);
      if (SPLITB)
        gload16((const char*)Blo + (size_t)(n0 + row) * rowB + kbyte + kb,
                (char*)Bl + (w * 2 + j) * 1024);
    }
    __syncthreads();
    bf16x8 af[4], bhf[4], blf[4];
#pragma unroll
    for (int i = 0; i < 4; ++i) {
      af[i]  = *(const bf16x8*)&As[(wr * 64 + i * 16 + lr) * 32 + lk * 8];
      bhf[i] = *(const bf16x8*)&Bh[(wc * 64 + i * 16 + lr) * 32 + lk * 8];
      if (SPLITB)
        blf[i] = *(const bf16x8*)&Bl[(wc * 64 + i * 16 + lr) * 32 + lk * 8];
    }
#pragma unroll
    for (int i = 0; i < 4; ++i)
#pragma unroll
      for (int j2 = 0; j2 < 4; ++j2) {
        acc[i][j2] = mfma16(af[i], bhf[j2], acc[i][j2]);
        if (SPLITB) acc[i][j2] = mfma16(af[i], blf[j2], acc[i][j2]);
      }
    __syncthreads();
  }
#pragma unroll
  for (int j2 = 0; j2 < 4; ++j2) {
    int n = n0 + wc * 64 + j2 * 16 + lr;
    float bv = bias ? bias[n] : 0.0f;
#pragma unroll
    for (int i = 0; i < 4; ++i) {
#pragma unroll
      for (int r = 0; r < 4; ++r) {
        int m = m0 + wr * 64 + i * 16 + lk * 4 + r;
        float v = acc[i][j2][r] + bv;
        if (RELU) v = fmaxf(v, 0.0f);
        if (OUTBF) Cb[(size_t)m * N + n] = f2bf(v);
        else       Cf[(size_t)m * N + n] = v;
      }
    }
  }
}

// ---------------- persistent scan kernel (fence-free scoped protocol) ----------
// 256 blocks x 256 threads; 4 independent row-groups (16 batch rows) x 64
// col-blocks (16 cols). Per barrier interval i:
//   phase A: h0(i)   = h0(i-1) + a0*tanh(P0[i] + Wh*h0(i-1))             [i<SEQ]
//   phase B: h1(i-1) = h1(i-2) + a1*tanh(Wi*h0(i-1) + Wh*h1(i-2) + b_c)  [i>=1]
// State exchanged via agent-scope relaxed atomics (MALL), flags packed 256B/group,
// no acquire fences (L1/L2 never invalidated -> weights/P0 stay cached).
__global__ __launch_bounds__(256, 1) void scan_kernel(
    const float* __restrict__ P0,
    const ushort_t* __restrict__ WiH, const ushort_t* __restrict__ WiL,
    const ushort_t* __restrict__ WhH, const ushort_t* __restrict__ WhL,
    const float* __restrict__ b_c, const float* __restrict__ taus,
    ushort_t* __restrict__ h0b,     // 2 x 64x1024 bf16 (double buffer)
    ushort_t* __restrict__ H1buf,   // SEQ x 64x1024 bf16 (archive = h1 state)
    float* __restrict__ outHidden, int* __restrict__ flags)
{
  const int blk = blockIdx.x;
  const int g = blk >> 6, c = blk & 63;
  const int tid = threadIdx.x;
  const int w = tid >> 6, l = tid & 63;
  const int lr = l & 15, lk = l >> 4;
  const int colg = c * 16;
  const int rowg = g * 16;
  const int kb = w * 256;

  __shared__ float red[2][4][64][5];   // [phase][wave][lane][reg(+pad)]

  // ---- one-time: weight slices into registers ----
  bf16x8 whh[8], whl[8], wih[8], wil[8];
#pragma unroll
  for (int kk = 0; kk < 8; ++kk) {
    size_t off = (size_t)(colg + lr) * HDIM + kb + kk * 32 + lk * 8;
    whh[kk] = *(const bf16x8*)&WhH[off];
    whl[kk] = *(const bf16x8*)&WhL[off];
    wih[kk] = *(const bf16x8*)&WiH[off];
    wil[kk] = *(const bf16x8*)&WiL[off];
  }

  const int R = l >> 2, jc = (l & 3) * 4;
  const int lo_base = 16 * (l >> 4);
  const int ro = (l >> 2) & 3;
  float hm0[4] = {0,0,0,0}, hm1[4] = {0,0,0,0};
  float bc4[4] = {0,0,0,0};
  float a0c = 0.f, a1c = 0.f;
  if (w == 0) {
#pragma unroll
    for (int j = 0; j < 4; ++j) bc4[j] = b_c[colg + jc + j];
    a0c = 0.05f / (taus[0] + 0.001f);
    a1c = 0.05f / (taus[1] + 0.001f);
  }
  int* myflag = &flags[g * 64 + c];

  // software-pipelined P0 tile (input-only, cached loads)
  float4 p0v = make_float4(0.f, 0.f, 0.f, 0.f);
  if (w == 0)
    p0v = *(const float4*)&P0[((size_t)0 * BATCH + rowg + R) * HDIM + colg + jc];

  for (int i = 0; i <= SEQ; ++i) {
    f32x4 aA0{}, aA1{}, aI0{}, aI1{}, aH0{}, aH1{};
    const ushort_t* h0r = h0b + ((i + 1) & 1) * (BATCH * HDIM);  // h0(i-1)
    if (i >= 1) {
#pragma unroll
      for (int kk = 0; kk < 8; ++kk) {
        bf16x8 a = aload16(&h0r[(size_t)(rowg + lr) * HDIM + kb + kk * 32 + lk * 8]);
        aA0 = mfma16(a, whh[kk], aA0);
        aA1 = mfma16(a, whl[kk], aA1);
        aI0 = mfma16(a, wih[kk], aI0);
        aI1 = mfma16(a, wil[kk], aI1);
      }
    }
    if (i >= 2) {
      const ushort_t* h1r = H1buf + (size_t)(i - 2) * (BATCH * HDIM);
#pragma unroll
      for (int kk = 0; kk < 8; ++kk) {
        bf16x8 a = aload16(&h1r[(size_t)(rowg + lr) * HDIM + kb + kk * 32 + lk * 8]);
        aH0 = mfma16(a, whh[kk], aH0);
        aH1 = mfma16(a, whl[kk], aH1);
      }
    }
    f32x4 pA = aA0 + aA1;
    f32x4 pB = (aI0 + aI1) + (aH0 + aH1);
#pragma unroll
    for (int r = 0; r < 4; ++r) {
      red[0][w][l][r] = pA[r];
      red[1][w][l][r] = pB[r];
    }
    __syncthreads();

    if (w == 0) {
      float sA[4], sB[4];
#pragma unroll
      for (int j = 0; j < 4; ++j) {
        float s0 = 0.f, s1 = 0.f;
#pragma unroll
        for (int w4 = 0; w4 < 4; ++w4) {
          s0 += red[0][w4][jc + j + lo_base][ro];
          s1 += red[1][w4][jc + j + lo_base][ro];
        }
        sA[j] = s0; sB[j] = s1;
      }
      if (i < SEQ) {
#pragma unroll
        for (int j = 0; j < 4; ++j)
          hm0[j] += a0c * tanhfast(p0v.x * (j == 0) + p0v.y * (j == 1) +
                                   p0v.z * (j == 2) + p0v.w * (j == 3) + sA[j]);
        ushort_t* h0w = h0b + (i & 1) * (BATCH * HDIM);
        __hip_atomic_store((ull_t*)&h0w[(size_t)(rowg + R) * HDIM + colg + jc],
                           pack4bf(hm0), __ATOMIC_RELAXED, __HIP_MEMORY_SCOPE_AGENT);
      }
      if (i >= 1) {
#pragma unroll
        for (int j = 0; j < 4; ++j)
          hm1[j] += a1c * tanhfast(sB[j] + bc4[j]);
        __hip_atomic_store((ull_t*)&H1buf[(size_t)(i - 1) * (BATCH * HDIM) +
                                          (size_t)(rowg + R) * HDIM + colg + jc],
                           pack4bf(hm1), __ATOMIC_RELAXED, __HIP_MEMORY_SCOPE_AGENT);
      }
      if (i < SEQ) {
        // order state stores before flag store (stores are agent-scope
        // write-through; vmcnt ack == visible at coherence point)
        asm volatile("s_waitcnt vmcnt(0)" ::: "memory");
        __hip_atomic_store(myflag, i + 1, __ATOMIC_RELAXED, __HIP_MEMORY_SCOPE_AGENT);
        // prefetch next P0 tile while others poll
        if (i + 1 < SEQ)
          p0v = *(const float4*)&P0[((size_t)(i + 1) * BATCH + rowg + R) * HDIM + colg + jc];
      }
    }
    if (i < SEQ) {
      if (w == 1) {
        const int target = i + 1;
        int v;
        for (;;) {
          v = __hip_atomic_load(&flags[g * 64 + l], __ATOMIC_RELAXED,
                                __HIP_MEMORY_SCOPE_AGENT);
          if (__all(v >= target)) break;
          __builtin_amdgcn_s_sleep(1);
        }
      }
      __syncthreads();
      asm volatile("" ::: "memory");   // compiler barrier only; no cache inval
    }
  }

  if (w == 0) {
    float4 o0 = make_float4(hm0[0], hm0[1], hm0[2], hm0[3]);
    float4 o1 = make_float4(hm1[0], hm1[1], hm1[2], hm1[3]);
    *(float4*)&outHidden[(size_t)(rowg + R) * HDIM + colg + jc] = o0;
    *(float4*)&outHidden[(size_t)(BATCH * HDIM) + (size_t)(rowg + R) * HDIM + colg + jc] = o1;
  }
}

// ---------------- host ----------------
extern "C" void kernel_launch(void* const* d_in, const int* in_sizes, int n_in,
                              void* d_out, int out_size, void* d_ws, size_t ws_size,
                              hipStream_t stream) {
  const float* x    = (const float*)d_in[0];
  const float* W_in = (const float*)d_in[1];
  const float* b_in = (const float*)d_in[2];
  const float* W_c  = (const float*)d_in[3];
  const float* b_c  = (const float*)d_in[4];
  const float* taus = (const float*)d_in[5];
  const float* W_o1 = (const float*)d_in[6];
  const float* b_o1 = (const float*)d_in[7];
  const float* W_o2 = (const float*)d_in[8];
  const float* b_o2 = (const float*)d_in[9];
  float* out = (float*)d_out;

  char* ws = (char*)d_ws;
  size_t off = 0;
  auto alloc = [&](size_t bytes) -> char* {
    char* p = ws + off;
    off += (bytes + 255) & ~(size_t)255;
    return p;
  };
  ushort_t* x_bf  = (ushort_t*)alloc((size_t)MTOT * INDIM * 2);
  ushort_t* xp_b  = (ushort_t*)alloc((size_t)MTOT * HDIM * 2);
  float*    P0    = (float*)   alloc((size_t)MTOT * HDIM * 4);
  ushort_t* H1buf = (ushort_t*)alloc((size_t)MTOT * HDIM * 2);
  ushort_t* O1    = (ushort_t*)alloc((size_t)MTOT * (HDIM/2) * 2);
  ushort_t* WiH   = (ushort_t*)alloc((size_t)HDIM * HDIM * 2);
  ushort_t* WiL   = (ushort_t*)alloc((size_t)HDIM * HDIM * 2);
  ushort_t* WhH   = (ushort_t*)alloc((size_t)HDIM * HDIM * 2);
  ushort_t* WhL   = (ushort_t*)alloc((size_t)HDIM * HDIM * 2);
  ushort_t* WinH  = (ushort_t*)alloc((size_t)HDIM * INDIM * 2);
  ushort_t* WinL  = (ushort_t*)alloc((size_t)HDIM * INDIM * 2);
  ushort_t* Wo1b  = (ushort_t*)alloc((size_t)(HDIM/2) * HDIM * 2);
  ushort_t* Wo2b  = (ushort_t*)alloc((size_t)OUTDIM * (HDIM/2) * 2);
  ushort_t* h0b   = (ushort_t*)alloc((size_t)2 * BATCH * HDIM * 2);
  int*      flags = (int*)     alloc(4096);
  if (off > ws_size) return;

  hipMemsetAsync(flags, 0, 4096, stream);

  k_convert<<<(MTOT * INDIM + 255) / 256, 256, 0, stream>>>(x, x_bf, MTOT * INDIM);
  k_split<<<(HDIM * INDIM + 255) / 256, 256, 0, stream>>>(W_in, WinH, WinL, HDIM * INDIM);
  k_split_wc<<<(HDIM * HDIM + 255) / 256, 256, 0, stream>>>(W_c, WiH, WiL, WhH, WhL);
  k_convert<<<((HDIM/2) * HDIM + 255) / 256, 256, 0, stream>>>(W_o1, Wo1b, (HDIM/2) * HDIM);
  k_convert<<<(OUTDIM * (HDIM/2) + 255) / 256, 256, 0, stream>>>(W_o2, Wo2b, OUTDIM * (HDIM/2));

  // xp = x @ W_in^T + b_in   -> bf16
  gemm_nt<1, 0, 1><<<dim3(MTOT / 128, HDIM / 128), 256, 0, stream>>>(
      x_bf, WinH, WinL, b_in, nullptr, xp_b, MTOT, HDIM, INDIM);
  // P0 = xp @ Wi^T + b_c     -> fp32
  gemm_nt<1, 0, 0><<<dim3(MTOT / 128, HDIM / 128), 256, 0, stream>>>(
      xp_b, WiH, WiL, b_c, P0, nullptr, MTOT, HDIM, HDIM);

  // sequential scan (4 independent row-groups x 64 blocks)
  scan_kernel<<<256, 256, 0, stream>>>(P0, WiH, WiL, WhH, WhL, b_c, taus,
                                       h0b, H1buf,
                                       out + (size_t)SEQ * BATCH * OUTDIM, flags);

  // O1 = relu(H1 @ W_o1^T + b_o1) -> bf16
  gemm_nt<0, 1, 1><<<dim3(MTOT / 128, (HDIM/2) / 128), 256, 0, stream>>>(
      H1buf, Wo1b, nullptr, b_o1, nullptr, O1, MTOT, HDIM / 2, HDIM);
  // out = O1 @ W_o2^T + b_o2 -> fp32
  gemm_nt<0, 0, 0><<<dim3(MTOT / 128, OUTDIM / 128), 256, 0, stream>>>(
      O1, Wo2b, nullptr, b_o2, out, nullptr, MTOT, OUTDIM, HDIM / 2);
}

// Round 5
// 1272.593 us; speedup vs baseline: 9.3223x; 2.0189x over previous
//
#include <hip/hip_runtime.h>
#include <hip/hip_bf16.h>
#include <stdint.h>

typedef unsigned short ushort_t;
typedef unsigned long long ull_t;
using bf16x8 = __attribute__((ext_vector_type(8))) short;
using f32x4  = __attribute__((ext_vector_type(4))) float;

#define SEQ    256
#define BATCH  64
#define INDIM  512
#define HDIM   1024
#define OUTDIM 256
#define MTOT   (SEQ*BATCH)   // 16384
#define BH     (BATCH*HDIM)

__device__ __forceinline__ ushort_t f2bf(float f) {
  uint32_t u = __builtin_bit_cast(uint32_t, f);
  u += 0x7fffu + ((u >> 16) & 1u);
  return (ushort_t)(u >> 16);
}
__device__ __forceinline__ float bf2f(ushort_t b) {
  uint32_t u = ((uint32_t)b) << 16;
  return __builtin_bit_cast(float, u);
}
__device__ __forceinline__ f32x4 mfma16(bf16x8 a, bf16x8 b, f32x4 c) {
  return __builtin_amdgcn_mfma_f32_16x16x32_bf16(a, b, c, 0, 0, 0);
}
__device__ __forceinline__ void gload16(const void* g, void* l) {
  __builtin_amdgcn_global_load_lds(
      (const __attribute__((address_space(1))) unsigned int*)g,
      (__attribute__((address_space(3))) unsigned int*)l, 16, 0, 0);
}
__device__ __forceinline__ float tanhfast(float z) {
  float e = __expf(2.0f * z);
  return 1.0f - 2.0f / (e + 1.0f);
}
__device__ __forceinline__ ull_t pack4bf(const float* v) {
  ull_t p = 0;
#pragma unroll
  for (int j = 0; j < 4; ++j) p |= (ull_t)f2bf(v[j]) << (16 * j);
  return p;
}

// ---------------- prep kernels ----------------
__global__ void k_convert(const float* __restrict__ src, ushort_t* __restrict__ dst, int n) {
  int i = blockIdx.x * blockDim.x + threadIdx.x;
  if (i < n) dst[i] = f2bf(src[i]);
}
__global__ void k_split(const float* __restrict__ src, ushort_t* __restrict__ hi,
                        ushort_t* __restrict__ lo, int n) {
  int i = blockIdx.x * blockDim.x + threadIdx.x;
  if (i < n) {
    float v = src[i];
    ushort_t h = f2bf(v);
    hi[i] = h;
    lo[i] = f2bf(v - bf2f(h));
  }
}
__global__ void k_split_wc(const float* __restrict__ Wc,
                           ushort_t* __restrict__ WiH, ushort_t* __restrict__ WiL,
                           ushort_t* __restrict__ WhH, ushort_t* __restrict__ WhL) {
  int i = blockIdx.x * blockDim.x + threadIdx.x;
  if (i < HDIM * HDIM) {
    int row = i >> 10, k = i & 1023;
    float vi = Wc[(size_t)row * (2 * HDIM) + k];
    float vh = Wc[(size_t)row * (2 * HDIM) + HDIM + k];
    ushort_t ih = f2bf(vi);
    WiH[i] = ih; WiL[i] = f2bf(vi - bf2f(ih));
    ushort_t hh = f2bf(vh);
    WhH[i] = hh; WhL[i] = f2bf(vh - bf2f(hh));
  }
}

// ---------------- generic NT GEMM (validated in r1-r3) ----------------
template<int SPLITB, int RELU, int OUTBF>
__global__ __launch_bounds__(256) void gemm_nt(
    const ushort_t* __restrict__ A, const ushort_t* __restrict__ Bhi,
    const ushort_t* __restrict__ Blo, const float* __restrict__ bias,
    float* __restrict__ Cf, ushort_t* __restrict__ Cb,
    int M, int N, int K)
{
  __shared__ ushort_t As[128 * 32];
  __shared__ ushort_t Bh[128 * 32];
  __shared__ ushort_t Bl[128 * 32];
  const int tid = threadIdx.x;
  const int w = tid >> 6, l = tid & 63;
  const int m0 = blockIdx.x * 128, n0 = blockIdx.y * 128;
  const int wr = w >> 1, wc = w & 1;
  const int lr = l & 15, lk = l >> 4;

  f32x4 acc[4][4] = {};
  const int nK = K >> 5;
  const size_t rowB = (size_t)K * 2;

  for (int kk = 0; kk < nK; ++kk) {
    const size_t kbyte = (size_t)kk * 64;
#pragma unroll
    for (int j = 0; j < 2; ++j) {
      int c = (w * 2 + j) * 64 + l;
      int row = c >> 2;
      int kb = (c & 3) * 16;
      gload16((const char*)A + (size_t)(m0 + row) * rowB + kbyte + kb,
              (char*)As + (w * 2 + j) * 1024);
      gload16((const char*)Bhi + (size_t)(n0 + row) * rowB + kbyte + kb,
              (char*)Bh + (w * 2 + j) * 1024);
      if (SPLITB)
        gload16((const char*)Blo + (size_t)(n0 + row) * rowB + kbyte + kb,
                (char*)Bl + (w * 2 + j) * 1024);
    }
    __syncthreads();
    bf16x8 af[4], bhf[4], blf[4];
#pragma unroll
    for (int i = 0; i < 4; ++i) {
      af[i]  = *(const bf16x8*)&As[(wr * 64 + i * 16 + lr) * 32 + lk * 8];
      bhf[i] = *(const bf16x8*)&Bh[(wc * 64 + i * 16 + lr) * 32 + lk * 8];
      if (SPLITB)
        blf[i] = *(const bf16x8*)&Bl[(wc * 64 + i * 16 + lr) * 32 + lk * 8];
    }
#pragma unroll
    for (int i = 0; i < 4; ++i)
#pragma unroll
      for (int j2 = 0; j2 < 4; ++j2) {
        acc[i][j2] = mfma16(af[i], bhf[j2], acc[i][j2]);
        if (SPLITB) acc[i][j2] = mfma16(af[i], blf[j2], acc[i][j2]);
      }
    __syncthreads();
  }
#pragma unroll
  for (int j2 = 0; j2 < 4; ++j2) {
    int n = n0 + wc * 64 + j2 * 16 + lr;
    float bv = bias ? bias[n] : 0.0f;
#pragma unroll
    for (int i = 0; i < 4; ++i) {
#pragma unroll
      for (int r = 0; r < 4; ++r) {
        int m = m0 + wr * 64 + i * 16 + lk * 4 + r;
        float v = acc[i][j2][r] + bv;
        if (RELU) v = fmaxf(v, 0.0f);
        if (OUTBF) Cb[(size_t)m * N + n] = f2bf(v);
        else       Cf[(size_t)m * N + n] = v;
      }
    }
  }
}

// ---------------- persistent scan kernel: XCD-local state, MALL flags --------
// Grid 512 x 512 threads (8 waves), 88KB LDS -> 1 block/CU. Each block reads
// its physical XCC_ID; blocks on XCDs 0-3 claim one of 32 slots (over-
// provisioned: every XCD hosts >=64 blocks during drain, so all groups always
// fill -> no hang). Group g owns batch rows 16g..16g+15; slot c owns cols
// 32c..32c+31. Bulk state: plain write-through stores + vmcnt(0) (lands in the
// group's shared per-XCD L2), plain first-touch loads (h0 archive is SEQ-deep
// so no address reuse -> L1 can never serve stale data). Flags: agent-scope
// atomics via MALL (r3-proven, hang-proof).
// Iter i: phase A: h0(i)   = h0(i-1) + a0*tanh(P0[i] + Wh0*h0(i-1))       [i<SEQ]
//         phase B: h1(i-1) = h1(i-2) + a1*tanh(Wi*h0(i-1)+Wh1*h1(i-2)+b_c) [i>=1]
__global__ __launch_bounds__(512, 2) void scan_kernel(
    const float* __restrict__ P0,
    const ushort_t* __restrict__ WiH, const ushort_t* __restrict__ WiL,
    const ushort_t* __restrict__ WhH, const ushort_t* __restrict__ WhL,
    const float* __restrict__ b_c, const float* __restrict__ taus,
    ushort_t* __restrict__ h0buf,   // SEQ x 64x1024 bf16 (archive, rotation)
    ushort_t* __restrict__ H1buf,   // SEQ x 64x1024 bf16 (archive = h1 state)
    float* __restrict__ outHidden, int* __restrict__ sync)
{
  __shared__ float red[2][2][8][64][11];   // [phase][ct][kslice][lane][reg+pad] ~88KB
  __shared__ int meta[2];

  const int tid = threadIdx.x;
  const int w = tid >> 6, l = tid & 63;
  const int lr = l & 15, lk = l >> 4;

  int* cnt   = sync;        // [8] per-XCD slot counters
  int* flags = sync + 64;   // [4][32] per-group flags

  // ---- placement discovery ----
  if (tid == 0) {
    int xcd;
    asm volatile("s_getreg_b32 %0, hwreg(HW_REG_XCC_ID)" : "=s"(xcd));
    int slot = 999;
    if (xcd < 4)
      slot = __hip_atomic_fetch_add(&cnt[xcd], 1, __ATOMIC_RELAXED,
                                    __HIP_MEMORY_SCOPE_AGENT);
    meta[0] = (xcd < 4) ? xcd : -1;
    meta[1] = slot;
  }
  __syncthreads();
  const int g = meta[0];
  const int c = meta[1];
  if (g < 0 || c >= 32) return;   // surplus block: exit, frees the CU

  const int rowg = g * 16, colg = c * 32;
  const int kb = w * 128;

  // ---- one-time: weight slices into registers (2 col-tiles x 4 frags x 4 mats)
  bf16x8 whh[2][4], whl[2][4], wih[2][4], wil[2][4];
#pragma unroll
  for (int ct = 0; ct < 2; ++ct)
#pragma unroll
    for (int kk = 0; kk < 4; ++kk) {
      size_t off = (size_t)(colg + ct * 16 + lr) * HDIM + kb + kk * 32 + lk * 8;
      whh[ct][kk] = *(const bf16x8*)&WhH[off];
      whl[ct][kk] = *(const bf16x8*)&WhL[off];
      wih[ct][kk] = *(const bf16x8*)&WiH[off];
      wil[ct][kk] = *(const bf16x8*)&WiL[off];
    }

  // epilogue mapping (waves 0,1; ct = w): lane -> row R, cols jc..jc+3
  const int R = l >> 2, jc = (l & 3) * 4;
  const int lo_base = 16 * (l >> 4);
  const int ro = (l >> 2) & 3;
  float hm0[4] = {0, 0, 0, 0}, hm1[4] = {0, 0, 0, 0};
  float bc4[4] = {0, 0, 0, 0};
  float a0c = 0.f, a1c = 0.f;
  float4 p0v = make_float4(0.f, 0.f, 0.f, 0.f);
  if (w < 2) {
#pragma unroll
    for (int j = 0; j < 4; ++j) bc4[j] = b_c[colg + w * 16 + jc + j];
    a0c = 0.05f / (taus[0] + 0.001f);
    a1c = 0.05f / (taus[1] + 0.001f);
    p0v = *(const float4*)&P0[((size_t)0 * BATCH + rowg + R) * HDIM + colg + w * 16 + jc];
  }

  for (int i = 0; i <= SEQ; ++i) {
    bf16x8 f[4], hh[4];
    f32x4 aA[2] = {}, aI[2] = {}, aH[2] = {};

    if (i >= 1) {
      const ushort_t* h0r = h0buf + (size_t)(i - 1) * BH;    // h0(i-1), first touch
#pragma unroll
      for (int kk = 0; kk < 4; ++kk)
        f[kk] = *(const bf16x8*)&h0r[(size_t)(rowg + lr) * HDIM + kb + kk * 32 + lk * 8];
      if (i >= 2) {
        const ushort_t* h1r = H1buf + (size_t)(i - 2) * BH;  // h1(i-2), first touch
#pragma unroll
        for (int kk = 0; kk < 4; ++kk)
          hh[kk] = *(const bf16x8*)&h1r[(size_t)(rowg + lr) * HDIM + kb + kk * 32 + lk * 8];
      }
#pragma unroll
      for (int kk = 0; kk < 4; ++kk)
#pragma unroll
        for (int ct = 0; ct < 2; ++ct) {
          aA[ct] = mfma16(f[kk], whh[ct][kk], aA[ct]);
          aA[ct] = mfma16(f[kk], whl[ct][kk], aA[ct]);
          aI[ct] = mfma16(f[kk], wih[ct][kk], aI[ct]);
          aI[ct] = mfma16(f[kk], wil[ct][kk], aI[ct]);
        }
      if (i >= 2) {
#pragma unroll
        for (int kk = 0; kk < 4; ++kk)
#pragma unroll
          for (int ct = 0; ct < 2; ++ct) {
            aH[ct] = mfma16(hh[kk], whh[ct][kk], aH[ct]);
            aH[ct] = mfma16(hh[kk], whl[ct][kk], aH[ct]);
          }
      }
    }
#pragma unroll
    for (int ct = 0; ct < 2; ++ct)
#pragma unroll
      for (int r = 0; r < 4; ++r) {
        red[0][ct][w][l][r] = aA[ct][r];
        red[1][ct][w][l][r] = aI[ct][r] + aH[ct][r];
      }
    __syncthreads();                                   // B1

    if (w < 2) {
      float sA[4], sB[4];
#pragma unroll
      for (int j = 0; j < 4; ++j) {
        const int src = jc + j + lo_base;
        float s0 = 0.f, s1 = 0.f;
#pragma unroll
        for (int q = 0; q < 8; ++q) {
          s0 += red[0][w][q][src][ro];
          s1 += red[1][w][q][src][ro];
        }
        sA[j] = s0; sB[j] = s1;
      }
      if (i < SEQ) {
        float p4[4] = {p0v.x, p0v.y, p0v.z, p0v.w};
#pragma unroll
        for (int j = 0; j < 4; ++j) hm0[j] += a0c * tanhfast(p4[j] + sA[j]);
        *(ull_t*)&h0buf[(size_t)i * BH + (size_t)(rowg + R) * HDIM +
                        colg + w * 16 + jc] = pack4bf(hm0);
      }
      if (i >= 1) {
#pragma unroll
        for (int j = 0; j < 4; ++j) hm1[j] += a1c * tanhfast(sB[j] + bc4[j]);
        *(ull_t*)&H1buf[(size_t)(i - 1) * BH + (size_t)(rowg + R) * HDIM +
                        colg + w * 16 + jc] = pack4bf(hm1);
      }
      asm volatile("s_waitcnt vmcnt(0)" ::: "memory"); // stores acked at L2
    }
    __syncthreads();                                   // B2

    if (i < SEQ) {
      if (tid == 0)
        __hip_atomic_store(&flags[g * 32 + c], i + 1, __ATOMIC_RELAXED,
                           __HIP_MEMORY_SCOPE_AGENT);
      if (w < 2 && i + 1 < SEQ)
        p0v = *(const float4*)&P0[((size_t)(i + 1) * BATCH + rowg + R) * HDIM +
                                  colg + w * 16 + jc];
      if (w == 2) {
        const int target = i + 1;
        for (;;) {
          int v = __hip_atomic_load(&flags[g * 32 + (l & 31)], __ATOMIC_RELAXED,
                                    __HIP_MEMORY_SCOPE_AGENT);
          if (__all(v >= target)) break;
          __builtin_amdgcn_s_sleep(1);
        }
      }
      __syncthreads();                                 // B3
    }
  }

  if (w < 2) {
    float4 o0 = make_float4(hm0[0], hm0[1], hm0[2], hm0[3]);
    float4 o1 = make_float4(hm1[0], hm1[1], hm1[2], hm1[3]);
    *(float4*)&outHidden[(size_t)(rowg + R) * HDIM + colg + w * 16 + jc] = o0;
    *(float4*)&outHidden[(size_t)BH + (size_t)(rowg + R) * HDIM + colg + w * 16 + jc] = o1;
  }
}

// ---------------- host ----------------
extern "C" void kernel_launch(void* const* d_in, const int* in_sizes, int n_in,
                              void* d_out, int out_size, void* d_ws, size_t ws_size,
                              hipStream_t stream) {
  const float* x    = (const float*)d_in[0];
  const float* W_in = (const float*)d_in[1];
  const float* b_in = (const float*)d_in[2];
  const float* W_c  = (const float*)d_in[3];
  const float* b_c  = (const float*)d_in[4];
  const float* taus = (const float*)d_in[5];
  const float* W_o1 = (const float*)d_in[6];
  const float* b_o1 = (const float*)d_in[7];
  const float* W_o2 = (const float*)d_in[8];
  const float* b_o2 = (const float*)d_in[9];
  float* out = (float*)d_out;

  char* ws = (char*)d_ws;
  size_t off = 0;
  auto alloc = [&](size_t bytes) -> char* {
    char* p = ws + off;
    off += (bytes + 255) & ~(size_t)255;
    return p;
  };
  ushort_t* x_bf  = (ushort_t*)alloc((size_t)MTOT * INDIM * 2);     // 16 MB
  ushort_t* xp_b  = (ushort_t*)alloc((size_t)MTOT * HDIM * 2);      // 32 MB
  float*    P0    = (float*)   alloc((size_t)MTOT * HDIM * 4);      // 64 MB
  ushort_t* H1buf = (ushort_t*)alloc((size_t)MTOT * HDIM * 2);      // 32 MB
  ushort_t* h0buf = (ushort_t*)alloc((size_t)SEQ * BH * 2);         // 32 MB
  ushort_t* O1    = (ushort_t*)alloc((size_t)MTOT * (HDIM/2) * 2);  // 16 MB
  ushort_t* WiH   = (ushort_t*)alloc((size_t)HDIM * HDIM * 2);
  ushort_t* WiL   = (ushort_t*)alloc((size_t)HDIM * HDIM * 2);
  ushort_t* WhH   = (ushort_t*)alloc((size_t)HDIM * HDIM * 2);
  ushort_t* WhL   = (ushort_t*)alloc((size_t)HDIM * HDIM * 2);
  ushort_t* WinH  = (ushort_t*)alloc((size_t)HDIM * INDIM * 2);
  ushort_t* WinL  = (ushort_t*)alloc((size_t)HDIM * INDIM * 2);
  ushort_t* Wo1b  = (ushort_t*)alloc((size_t)(HDIM/2) * HDIM * 2);
  ushort_t* Wo2b  = (ushort_t*)alloc((size_t)OUTDIM * (HDIM/2) * 2);
  int*      sync  = (int*)     alloc(4096);
  if (off > ws_size) return;

  hipMemsetAsync(sync, 0, 4096, stream);

  k_convert<<<(MTOT * INDIM + 255) / 256, 256, 0, stream>>>(x, x_bf, MTOT * INDIM);
  k_split<<<(HDIM * INDIM + 255) / 256, 256, 0, stream>>>(W_in, WinH, WinL, HDIM * INDIM);
  k_split_wc<<<(HDIM * HDIM + 255) / 256, 256, 0, stream>>>(W_c, WiH, WiL, WhH, WhL);
  k_convert<<<((HDIM/2) * HDIM + 255) / 256, 256, 0, stream>>>(W_o1, Wo1b, (HDIM/2) * HDIM);
  k_convert<<<(OUTDIM * (HDIM/2) + 255) / 256, 256, 0, stream>>>(W_o2, Wo2b, OUTDIM * (HDIM/2));

  // xp = x @ W_in^T + b_in   -> bf16
  gemm_nt<1, 0, 1><<<dim3(MTOT / 128, HDIM / 128), 256, 0, stream>>>(
      x_bf, WinH, WinL, b_in, nullptr, xp_b, MTOT, HDIM, INDIM);
  // P0 = xp @ Wi^T + b_c     -> fp32
  gemm_nt<1, 0, 0><<<dim3(MTOT / 128, HDIM / 128), 256, 0, stream>>>(
      xp_b, WiH, WiL, b_c, P0, nullptr, MTOT, HDIM, HDIM);

  // sequential scan: 4 XCD-local groups x 32 worker blocks (over-provisioned grid)
  scan_kernel<<<512, 512, 0, stream>>>(P0, WiH, WiL, WhH, WhL, b_c, taus,
                                       h0buf, H1buf,
                                       out + (size_t)SEQ * BATCH * OUTDIM, sync);

  // O1 = relu(H1 @ W_o1^T + b_o1) -> bf16
  gemm_nt<0, 1, 1><<<dim3(MTOT / 128, (HDIM/2) / 128), 256, 0, stream>>>(
      H1buf, Wo1b, nullptr, b_o1, nullptr, O1, MTOT, HDIM / 2, HDIM);
  // out = O1 @ W_o2^T + b_o2 -> fp32
  gemm_nt<0, 0, 0><<<dim3(MTOT / 128, OUTDIM / 128), 256, 0, stream>>>(
      O1, Wo2b, nullptr, b_o2, out, nullptr, MTOT, OUTDIM, HDIM / 2);
}